// Round 14
// baseline (14.521 us; speedup 1.0000x reference)
//
#include <hip/hip_runtime.h>
#include <math.h>

#define PRE_LEN 64
#define BATCH   1024
#define NNB     256

typedef float v2f __attribute__((ext_vector_type(2)));

// Math (validated R4-R13, absmax 0.0):
//   rotation preserves norm: x^2+y^2 = r2
//   x^6+y^6 = r2*(r2^2 - 3*xy^2);  xy = dx*dy*cos2a - (dx^2-dy^2)*(ca*sa)
//   sqrt(3) folded into staged coeffs: xyS = sqrt3*xy -> inr = r4 - xyS^2
//   energy_i/r = rsq(den^2*r2); 60x applied once in the tail.
//
// R14 = R13 + two levers:
//  (A) FULL unroll of the 32-iter loop (interleaves the independent rsq
//      chains; no loop-carried deps except the 8 accumulators).
//  (D) DEEP blocks: 512 blocks, each processes 2 consecutive batches in the
//      same loop pass. Halves block count (ramp/tail skew), keeps the
//      R13 barrier-free wave-local staging (wave q stages AND reads
//      s_nb[g][64q..64q+64) for g=0,1), one shared barrier, and the two
//      tails run in PARALLEL on waves 0 and 1. 4 independent chains/iter
//      covers latency at 2 waves/SIMD (R11: 2/SIMD is sufficient).
__global__ __launch_bounds__(256, 4) void field_loss_stage1(
    const float* __restrict__ output,   // [PRE_LEN][BATCH][2]
    const float* __restrict__ target,   // [PRE_LEN][BATCH][2]
    const float* __restrict__ nbr,      // [BATCH][NNB][5]
    float* __restrict__ ws)             // [BATCH] partials
{
    __shared__ float4 s_nb[2][NNB];     // {nx,ny,sqrt3*cos2a,sqrt3*ca*sa} x2
    __shared__ float4 s_red[2][4][32];  // {ex0,ey0,ex1,ey1} per (batch,wave,p)

    const int b0  = 2 * blockIdx.x;     // this block's two batches: b0, b0+1
    const int tid = threadIdx.x;
    const int l   = tid & 63;
    const int q   = tid >> 6;           // wave 0..3
    const int p   = l & 31;             // t-pair index
    const int t0  = 2 * p;

    // Strided output loads for BOTH batches issued first (latency hides
    // under staging + sincos).
    const size_t oA = (size_t)t0 * (BATCH * 2) + (size_t)b0 * 2;  // t0, b0
    const size_t oB = oA + (BATCH * 2);                            // t1, b0
    const float2 aA0 = *reinterpret_cast<const float2*>(&output[oA]);
    const float2 aB0 = *reinterpret_cast<const float2*>(&output[oB]);
    const float2 aA1 = *reinterpret_cast<const float2*>(&output[oA + 2]);
    const float2 aB1 = *reinterpret_cast<const float2*>(&output[oB + 2]);
    // target: wave 0 finalizes batch 0, wave 1 finalizes batch 1
    float2 tgA = make_float2(0.f, 0.f), tgB = make_float2(0.f, 0.f);
    if (q < 2) {
        tgA = *reinterpret_cast<const float2*>(&target[oA + 2 * q]);
        tgB = *reinterpret_cast<const float2*>(&target[oB + 2 * q]);
    }

    {   // wave-local staging, both batches: thread 64q+l stages neighbour
        // 64q+l of b0 and b0+1 — exactly the ranges wave q's loop reads.
        #pragma unroll
        for (int g = 0; g < 2; ++g) {
            const float* pn = nbr + (((size_t)(b0 + g)) * NNB + tid) * 5;
            const float nx  = pn[0];
            const float ny  = pn[1];
            const float ang = pn[4];
            const float rev = ang * 0.31830988618f;         // (2a)/(2*pi)
            const float c2  = __builtin_amdgcn_cosf(rev);   // cos(2a)
            const float s2  = __builtin_amdgcn_sinf(rev);   // sin(2a)
            s_nb[g][tid] = make_float4(nx, ny, 1.7320508f * c2,
                                       0.86602540f * s2);   // sqrt3*{c2,ca*sa}
        }
    }
    // fence compiler reordering only (same-wave LDS ops complete in order)
    asm volatile("" ::: "memory");
    __builtin_amdgcn_sched_barrier(0);

    const v2f px0 = { aA0.x, aB0.x };   // batch 0, timesteps t0/t1
    const v2f py0 = { aA0.y, aB0.y };
    const v2f px1 = { aA1.x, aB1.x };   // batch 1
    const v2f py1 = { aA1.y, aB1.y };

    v2f ex0 = 0.0f, ey0 = 0.0f, ex1 = 0.0f, ey1 = 0.0f;
    const int n0 = ((l >> 5) + 2 * q) * 32;   // chunks 2q,2q+1: wave-local
#pragma unroll
    for (int i = 0; i < 32; ++i) {
        {   // batch 0
            const float4 nb = s_nb[0][n0 + i];   // 2-addr broadcast (free)
            const v2f dx  = px0 - nb.x;
            const v2f dy  = py0 - nb.y;
            const v2f dx2 = dx * dx;
            const v2f pp  = dx * dy;
            const v2f r2  = __builtin_elementwise_fma(dy, dy, dx2);
            const v2f qq  = __builtin_elementwise_fma(dy, -dy, dx2);
            const v2f xyS = __builtin_elementwise_fma(pp, (v2f)nb.z,
                                                      -(qq * nb.w));
            const v2f inr = __builtin_elementwise_fma(-xyS, xyS, r2 * r2);
            const v2f den = __builtin_elementwise_fma(r2, inr, (v2f)6.0f);
            const v2f m2  = den * den * r2;
            const v2f s   = { __builtin_amdgcn_rsqf(m2.x),
                              __builtin_amdgcn_rsqf(m2.y) };
            ex0 = __builtin_elementwise_fma(s, dx, ex0);
            ey0 = __builtin_elementwise_fma(s, dy, ey0);
        }
        {   // batch 1
            const float4 nb = s_nb[1][n0 + i];
            const v2f dx  = px1 - nb.x;
            const v2f dy  = py1 - nb.y;
            const v2f dx2 = dx * dx;
            const v2f pp  = dx * dy;
            const v2f r2  = __builtin_elementwise_fma(dy, dy, dx2);
            const v2f qq  = __builtin_elementwise_fma(dy, -dy, dx2);
            const v2f xyS = __builtin_elementwise_fma(pp, (v2f)nb.z,
                                                      -(qq * nb.w));
            const v2f inr = __builtin_elementwise_fma(-xyS, xyS, r2 * r2);
            const v2f den = __builtin_elementwise_fma(r2, inr, (v2f)6.0f);
            const v2f m2  = den * den * r2;
            const v2f s   = { __builtin_amdgcn_rsqf(m2.x),
                              __builtin_amdgcn_rsqf(m2.y) };
            ex1 = __builtin_elementwise_fma(s, dx, ex1);
            ey1 = __builtin_elementwise_fma(s, dy, ey1);
        }
    }

    // combine half-waves (lane l and l^32 share p, differ in chunk)
    const float e0x0 = ex0.x + __shfl_xor(ex0.x, 32, 64);
    const float e0y0 = ey0.x + __shfl_xor(ey0.x, 32, 64);
    const float e0x1 = ex0.y + __shfl_xor(ex0.y, 32, 64);
    const float e0y1 = ey0.y + __shfl_xor(ey0.y, 32, 64);
    const float e1x0 = ex1.x + __shfl_xor(ex1.x, 32, 64);
    const float e1y0 = ey1.x + __shfl_xor(ey1.x, 32, 64);
    const float e1x1 = ex1.y + __shfl_xor(ex1.y, 32, 64);
    const float e1y1 = ey1.y + __shfl_xor(ey1.y, 32, 64);

    if (l < 32) {
        s_red[0][q][p] = make_float4(e0x0, e0y0, e0x1, e0y1);
        s_red[1][q][p] = make_float4(e1x0, e1y0, e1x1, e1y1);
    }
    __syncthreads();                    // the one barrier

    if (q < 2) {                        // wave q finalizes batch q (parallel)
        float tex0 = 0.0f, tey0 = 0.0f, tex1 = 0.0f, tey1 = 0.0f;
        #pragma unroll
        for (int k = 0; k < 4; ++k) {
            const float4 r = s_red[q][k][p];
            tex0 += r.x; tey0 += r.y; tex1 += r.z; tey1 += r.w;
        }
        const float en0 = __builtin_amdgcn_sqrtf(
            __builtin_fmaf(tex0, tex0, tey0 * tey0));
        const float en1 = __builtin_amdgcn_sqrtf(
            __builtin_fmaf(tex1, tex1, tey1 * tey1));

        const float2 pA = (q == 0) ? aA0 : aA1;
        const float2 pB = (q == 0) ? aB0 : aB1;
        const float d0x = pA.x - tgA.x, d0y = pA.y - tgA.y;
        const float d1x = pB.x - tgB.x, d1y = pB.y - tgB.y;

        float val = (en0 + en1) * (60.0f / (PRE_LEN * BATCH))
                  + (d0x * d0x + d0y * d0y + d1x * d1x + d1y * d1y)
                    * (1.0f / (PRE_LEN * BATCH * 2));

        // lanes 0-31 hold the 32 distinct vals (32-63 duplicate)
        #pragma unroll
        for (int off = 16; off > 0; off >>= 1)
            val += __shfl_down(val, off, 64);

        if (l == 0)
            ws[b0 + q] = val;           // plain store, one per batch
    }
}

// Stage 2: ONE wave, no LDS, no barrier. 1024 floats = 256 float4.
__global__ __launch_bounds__(64) void reduce_kernel(
    const float4* __restrict__ ws4,  // [256]
    float* __restrict__ out)         // [1]
{
    const int l = threadIdx.x;
    const float4 a = ws4[l];
    const float4 b = ws4[l + 64];
    const float4 c = ws4[l + 128];
    const float4 d = ws4[l + 192];
    float v = ((a.x + a.y) + (a.z + a.w)) + ((b.x + b.y) + (b.z + b.w))
            + ((c.x + c.y) + (c.z + c.w)) + ((d.x + d.y) + (d.z + d.w));

    #pragma unroll
    for (int off = 32; off > 0; off >>= 1)
        v += __shfl_down(v, off, 64);

    if (l == 0)
        out[0] = v;
}

extern "C" void kernel_launch(void* const* d_in, const int* in_sizes, int n_in,
                              void* d_out, int out_size, void* d_ws, size_t ws_size,
                              hipStream_t stream) {
    const float* output = (const float*)d_in[0];
    const float* target = (const float*)d_in[1];
    const float* nbr    = (const float*)d_in[2];
    float* out = (float*)d_out;
    float* ws  = (float*)d_ws;      // >= 1024 floats, 16B-aligned

    field_loss_stage1<<<dim3(BATCH / 2), dim3(256), 0, stream>>>(output, target, nbr, ws);
    reduce_kernel<<<dim3(1), dim3(64), 0, stream>>>((const float4*)ws, out);
}

// Round 15
// 14.263 us; speedup vs baseline: 1.0181x; 1.0181x over previous
//
#include <hip/hip_runtime.h>
#include <math.h>

#define PRE_LEN 64
#define BATCH   1024
#define NNB     256

typedef float v2f __attribute__((ext_vector_type(2)));

// Math (validated R4-R14, absmax 0.0):
//   rotation preserves norm: x^2+y^2 = r2
//   x^6+y^6 = r2*(r2^2 - 3*xy^2);  xy = dx*dy*cos2a - (dx^2-dy^2)*(ca*sa)
//   sqrt(3) folded into staged coeffs: xyS = sqrt3*xy -> inr = r4 - xyS^2
//   energy_i/r = rsq(den^2*r2); 60x applied once in the tail.
//
// R15 = R13 (best, 13.61us) with ONE isolated change: FULL unroll of the
// 32-iter loop (R14 bundled it with deep blocks and regressed; untangle).
// Full unroll lets the scheduler hoist ds_read_b128s arbitrarily far ahead
// (deeper LDS MLP than the 8-deep pragma window) and interleave the 64
// independent rsq dependency chains.
__global__ __launch_bounds__(256, 4) void field_loss_stage1(
    const float* __restrict__ output,   // [PRE_LEN][BATCH][2]
    const float* __restrict__ target,   // [PRE_LEN][BATCH][2]
    const float* __restrict__ nbr,      // [BATCH][NNB][5]
    float* __restrict__ ws)             // [BATCH] partials
{
    __shared__ float4 s_nb[NNB];        // {nx, ny, sqrt3*cos2a, sqrt3*ca*sa}
    __shared__ float4 s_red[4][32];     // {ex0,ey0,ex1,ey1} per (wave, p)

    const int b   = blockIdx.x;
    const int tid = threadIdx.x;
    const int l   = tid & 63;
    const int q   = tid >> 6;           // wave 0..3
    const int p   = l & 31;             // t-pair index
    const int t0  = 2 * p;

    // Strided output loads issued first (latency hides under staging+sincos).
    const size_t o0 = (size_t)t0 * (BATCH * 2) + (size_t)b * 2;
    const size_t o1 = o0 + (BATCH * 2);
    const float2 a0 = *reinterpret_cast<const float2*>(&output[o0]);
    const float2 a1 = *reinterpret_cast<const float2*>(&output[o1]);
    float2 tg0 = make_float2(0.f, 0.f), tg1 = make_float2(0.f, 0.f);
    if (q == 0) {                       // target only consumed by the tail wave
        tg0 = *reinterpret_cast<const float2*>(&target[o0]);
        tg1 = *reinterpret_cast<const float2*>(&target[o1]);
    }

    {   // wave-local staging: thread 64q+l stages neighbour 64q+l, which is
        // exactly the range wave q's loop reads. No __syncthreads needed.
        const float* pn = nbr + ((size_t)b * NNB + tid) * 5;
        const float nx  = pn[0];
        const float ny  = pn[1];
        const float ang = pn[4];
        const float rev = ang * 0.31830988618f;         // (2a)/(2*pi)
        const float c2  = __builtin_amdgcn_cosf(rev);   // cos(2a)
        const float s2  = __builtin_amdgcn_sinf(rev);   // sin(2a)
        s_nb[tid] = make_float4(nx, ny, 1.7320508f * c2,
                                0.86602540f * s2);      // sqrt3*{c2, 0.5*s2}
    }
    // fence compiler reordering of ds_read before ds_write (HW processes a
    // wave's LDS ops in order; only code motion must be prevented).
    asm volatile("" ::: "memory");
    __builtin_amdgcn_sched_barrier(0);

    const v2f px = { a0.x, a1.x };
    const v2f py = { a0.y, a1.y };

    v2f ex = 0.0f, ey = 0.0f;
    const int n0 = ((l >> 5) + 2 * q) * 32;   // chunks 2q,2q+1: wave-local
#pragma unroll
    for (int i = 0; i < 32; ++i) {
        const float4 nb = s_nb[n0 + i];       // 2-addr broadcast (free, m136)
        const v2f dx  = px - nb.x;
        const v2f dy  = py - nb.y;
        const v2f dx2 = dx * dx;
        const v2f pp  = dx * dy;
        const v2f r2  = __builtin_elementwise_fma(dy, dy, dx2);
        const v2f qq  = __builtin_elementwise_fma(dy, -dy, dx2);  // dx^2-dy^2
        const v2f xyS = __builtin_elementwise_fma(pp, (v2f)nb.z,
                                                  -(qq * nb.w));  // sqrt3*xy
        const v2f inr = __builtin_elementwise_fma(-xyS, xyS, r2 * r2);
        const v2f den = __builtin_elementwise_fma(r2, inr, (v2f)6.0f);
        const v2f m2  = den * den * r2;
        const v2f s   = { __builtin_amdgcn_rsqf(m2.x),
                          __builtin_amdgcn_rsqf(m2.y) };
        ex = __builtin_elementwise_fma(s, dx, ex);
        ey = __builtin_elementwise_fma(s, dy, ey);
    }

    // combine half-waves (lane l and l^32 share p, differ in chunk)
    const float ex0 = ex.x + __shfl_xor(ex.x, 32, 64);
    const float ey0 = ey.x + __shfl_xor(ey.x, 32, 64);
    const float ex1 = ex.y + __shfl_xor(ex.y, 32, 64);
    const float ey1 = ey.y + __shfl_xor(ey.y, 32, 64);

    if (l < 32)
        s_red[q][p] = make_float4(ex0, ey0, ex1, ey1);
    __syncthreads();                    // the one remaining barrier

    if (q == 0) {
        float tex0 = 0.0f, tey0 = 0.0f, tex1 = 0.0f, tey1 = 0.0f;
        #pragma unroll
        for (int k = 0; k < 4; ++k) {
            const float4 r = s_red[k][p];
            tex0 += r.x; tey0 += r.y; tex1 += r.z; tey1 += r.w;
        }
        const float en0 = __builtin_amdgcn_sqrtf(
            __builtin_fmaf(tex0, tex0, tey0 * tey0));
        const float en1 = __builtin_amdgcn_sqrtf(
            __builtin_fmaf(tex1, tex1, tey1 * tey1));

        const float d0x = a0.x - tg0.x, d0y = a0.y - tg0.y;
        const float d1x = a1.x - tg1.x, d1y = a1.y - tg1.y;

        float val = (en0 + en1) * (60.0f / (PRE_LEN * BATCH))
                  + (d0x * d0x + d0y * d0y + d1x * d1x + d1y * d1y)
                    * (1.0f / (PRE_LEN * BATCH * 2));

        // lanes 0-31 hold the 32 distinct vals (32-63 duplicate)
        #pragma unroll
        for (int off = 16; off > 0; off >>= 1)
            val += __shfl_down(val, off, 64);

        if (l == 0)
            ws[b] = val;                // plain store, one per block
    }
}

// Stage 2: ONE wave, no LDS, no barrier. 1024 floats = 256 float4.
__global__ __launch_bounds__(64) void reduce_kernel(
    const float4* __restrict__ ws4,  // [256]
    float* __restrict__ out)         // [1]
{
    const int l = threadIdx.x;
    const float4 a = ws4[l];
    const float4 b = ws4[l + 64];
    const float4 c = ws4[l + 128];
    const float4 d = ws4[l + 192];
    float v = ((a.x + a.y) + (a.z + a.w)) + ((b.x + b.y) + (b.z + b.w))
            + ((c.x + c.y) + (c.z + c.w)) + ((d.x + d.y) + (d.z + d.w));

    #pragma unroll
    for (int off = 32; off > 0; off >>= 1)
        v += __shfl_down(v, off, 64);

    if (l == 0)
        out[0] = v;
}

extern "C" void kernel_launch(void* const* d_in, const int* in_sizes, int n_in,
                              void* d_out, int out_size, void* d_ws, size_t ws_size,
                              hipStream_t stream) {
    const float* output = (const float*)d_in[0];
    const float* target = (const float*)d_in[1];
    const float* nbr    = (const float*)d_in[2];
    float* out = (float*)d_out;
    float* ws  = (float*)d_ws;      // >= 1024 floats, 16B-aligned

    field_loss_stage1<<<dim3(BATCH), dim3(256), 0, stream>>>(output, target, nbr, ws);
    reduce_kernel<<<dim3(1), dim3(64), 0, stream>>>((const float4*)ws, out);
}

// Round 16
// 13.537 us; speedup vs baseline: 1.0727x; 1.0536x over previous
//
#include <hip/hip_runtime.h>
#include <math.h>

#define PRE_LEN 64
#define BATCH   1024
#define NNB     256

typedef float v2f __attribute__((ext_vector_type(2)));

// FINAL (R16 = R13, the session best: 13.61us, absmax 0.0).
//
// Math (validated R4-R15):
//   rotation preserves norm: x^2+y^2 = r2
//   x^6+y^6 = r2*(r2^2 - 3*xy^2);  xy = dx*dy*cos2a - (dx^2-dy^2)*(ca*sa)
//   sqrt(3) folded into staged coeffs: xyS = sqrt3*xy -> inr = r4 - xyS^2
//   energy_i/r = rsq(den^2*r2); 60x applied once in the tail.
//
// Structure (each element A/B-validated across R1-R15):
//   - two dispatches: 1024x256 stage1 + 1-wave reduce (every single-dispatch
//     finalizer falsified: grid.sync +70us, acq_rel last-block +25us,
//     sync'd same-line atomics +7us, release/spin checksum +7us)
//   - 4 waves/block, lane l: t-pair p=l&31 -> t0=2p,2p+1; chunk (l>>5)+2q;
//     32 iters, packed v2f math (v_pk_fma_f32)
//   - barrier-free wave-local staging: thread 64q+l stages neighbour 64q+l,
//     exactly the range wave q reads; only compiler reordering is fenced
//   - #pragma unroll 8 (full unroll regressed: +0.65us R15)
__global__ __launch_bounds__(256, 4) void field_loss_stage1(
    const float* __restrict__ output,   // [PRE_LEN][BATCH][2]
    const float* __restrict__ target,   // [PRE_LEN][BATCH][2]
    const float* __restrict__ nbr,      // [BATCH][NNB][5]
    float* __restrict__ ws)             // [BATCH] partials
{
    __shared__ float4 s_nb[NNB];        // {nx, ny, sqrt3*cos2a, sqrt3*ca*sa}
    __shared__ float4 s_red[4][32];     // {ex0,ey0,ex1,ey1} per (wave, p)

    const int b   = blockIdx.x;
    const int tid = threadIdx.x;
    const int l   = tid & 63;
    const int q   = tid >> 6;           // wave 0..3
    const int p   = l & 31;             // t-pair index
    const int t0  = 2 * p;

    // Strided output loads issued first (latency hides under staging+sincos).
    const size_t o0 = (size_t)t0 * (BATCH * 2) + (size_t)b * 2;
    const size_t o1 = o0 + (BATCH * 2);
    const float2 a0 = *reinterpret_cast<const float2*>(&output[o0]);
    const float2 a1 = *reinterpret_cast<const float2*>(&output[o1]);
    float2 tg0 = make_float2(0.f, 0.f), tg1 = make_float2(0.f, 0.f);
    if (q == 0) {                       // target only consumed by the tail wave
        tg0 = *reinterpret_cast<const float2*>(&target[o0]);
        tg1 = *reinterpret_cast<const float2*>(&target[o1]);
    }

    {   // wave-local staging: thread 64q+l stages neighbour 64q+l, which is
        // exactly the range wave q's loop reads. No __syncthreads needed.
        const float* pn = nbr + ((size_t)b * NNB + tid) * 5;
        const float nx  = pn[0];
        const float ny  = pn[1];
        const float ang = pn[4];
        const float rev = ang * 0.31830988618f;         // (2a)/(2*pi)
        const float c2  = __builtin_amdgcn_cosf(rev);   // cos(2a)
        const float s2  = __builtin_amdgcn_sinf(rev);   // sin(2a)
        s_nb[tid] = make_float4(nx, ny, 1.7320508f * c2,
                                0.86602540f * s2);      // sqrt3*{c2, 0.5*s2}
    }
    // fence compiler reordering of ds_read before ds_write (HW processes a
    // wave's LDS ops in order; only code motion must be prevented).
    asm volatile("" ::: "memory");
    __builtin_amdgcn_sched_barrier(0);

    const v2f px = { a0.x, a1.x };
    const v2f py = { a0.y, a1.y };

    v2f ex = 0.0f, ey = 0.0f;
    const int n0 = ((l >> 5) + 2 * q) * 32;   // chunks 2q,2q+1: wave-local
#pragma unroll 8
    for (int i = 0; i < 32; ++i) {
        const float4 nb = s_nb[n0 + i];       // 2-addr broadcast (free, m136)
        const v2f dx  = px - nb.x;
        const v2f dy  = py - nb.y;
        const v2f dx2 = dx * dx;
        const v2f pp  = dx * dy;
        const v2f r2  = __builtin_elementwise_fma(dy, dy, dx2);
        const v2f qq  = __builtin_elementwise_fma(dy, -dy, dx2);  // dx^2-dy^2
        const v2f xyS = __builtin_elementwise_fma(pp, (v2f)nb.z,
                                                  -(qq * nb.w));  // sqrt3*xy
        const v2f inr = __builtin_elementwise_fma(-xyS, xyS, r2 * r2);
        const v2f den = __builtin_elementwise_fma(r2, inr, (v2f)6.0f);
        const v2f m2  = den * den * r2;
        const v2f s   = { __builtin_amdgcn_rsqf(m2.x),
                          __builtin_amdgcn_rsqf(m2.y) };
        ex = __builtin_elementwise_fma(s, dx, ex);
        ey = __builtin_elementwise_fma(s, dy, ey);
    }

    // combine half-waves (lane l and l^32 share p, differ in chunk)
    const float ex0 = ex.x + __shfl_xor(ex.x, 32, 64);
    const float ey0 = ey.x + __shfl_xor(ey.x, 32, 64);
    const float ex1 = ex.y + __shfl_xor(ex.y, 32, 64);
    const float ey1 = ey.y + __shfl_xor(ey.y, 32, 64);

    if (l < 32)
        s_red[q][p] = make_float4(ex0, ey0, ex1, ey1);
    __syncthreads();                    // the one remaining barrier

    if (q == 0) {
        float tex0 = 0.0f, tey0 = 0.0f, tex1 = 0.0f, tey1 = 0.0f;
        #pragma unroll
        for (int k = 0; k < 4; ++k) {
            const float4 r = s_red[k][p];
            tex0 += r.x; tey0 += r.y; tex1 += r.z; tey1 += r.w;
        }
        const float en0 = __builtin_amdgcn_sqrtf(
            __builtin_fmaf(tex0, tex0, tey0 * tey0));
        const float en1 = __builtin_amdgcn_sqrtf(
            __builtin_fmaf(tex1, tex1, tey1 * tey1));

        const float d0x = a0.x - tg0.x, d0y = a0.y - tg0.y;
        const float d1x = a1.x - tg1.x, d1y = a1.y - tg1.y;

        float val = (en0 + en1) * (60.0f / (PRE_LEN * BATCH))
                  + (d0x * d0x + d0y * d0y + d1x * d1x + d1y * d1y)
                    * (1.0f / (PRE_LEN * BATCH * 2));

        // lanes 0-31 hold the 32 distinct vals (32-63 duplicate)
        #pragma unroll
        for (int off = 16; off > 0; off >>= 1)
            val += __shfl_down(val, off, 64);

        if (l == 0)
            ws[b] = val;                // plain store, one per block
    }
}

// Stage 2: ONE wave, no LDS, no barrier. 1024 floats = 256 float4.
__global__ __launch_bounds__(64) void reduce_kernel(
    const float4* __restrict__ ws4,  // [256]
    float* __restrict__ out)         // [1]
{
    const int l = threadIdx.x;
    const float4 a = ws4[l];
    const float4 b = ws4[l + 64];
    const float4 c = ws4[l + 128];
    const float4 d = ws4[l + 192];
    float v = ((a.x + a.y) + (a.z + a.w)) + ((b.x + b.y) + (b.z + b.w))
            + ((c.x + c.y) + (c.z + c.w)) + ((d.x + d.y) + (d.z + d.w));

    #pragma unroll
    for (int off = 32; off > 0; off >>= 1)
        v += __shfl_down(v, off, 64);

    if (l == 0)
        out[0] = v;
}

extern "C" void kernel_launch(void* const* d_in, const int* in_sizes, int n_in,
                              void* d_out, int out_size, void* d_ws, size_t ws_size,
                              hipStream_t stream) {
    const float* output = (const float*)d_in[0];
    const float* target = (const float*)d_in[1];
    const float* nbr    = (const float*)d_in[2];
    float* out = (float*)d_out;
    float* ws  = (float*)d_ws;      // >= 1024 floats, 16B-aligned

    field_loss_stage1<<<dim3(BATCH), dim3(256), 0, stream>>>(output, target, nbr, ws);
    reduce_kernel<<<dim3(1), dim3(64), 0, stream>>>((const float4*)ws, out);
}